// Round 1
// baseline (580.096 us; speedup 1.0000x reference)
//
#include <hip/hip_runtime.h>
#include <hip/hip_fp16.h>
#include <math.h>

// NormVoxels R6: S-form accumulation -> halo events are gather-free.
//  brick_kernel was latency/transaction-bound (HBM 30%, VALU 17%, conflicts 0):
//  - accumulate (S_lam, S_lam*target) per owned voxel instead of lam*(t - a);
//    corner value 'a' folds in at writeback: out = a + S_lamt - S_lam*a.
//    Halo events (55% of 2.25M events) no longer issue 8 global gathers each
//    (18M -> 8M gather lane-transactions). s_acc 24.6KB -> 32.8KB (6->4 WG/CU).
//  - binary search over 25-bin prefix (5 LDS probes vs avg-13 linear).
//  - __expf sigmoid (v_exp_f32) instead of libm expf.
//  - scanB dropped: scanC reduces partial[0..blockIdx) itself (L2-hot, 2KB).
// d_in: [0]=t(i32,N) [1]=pos(f32,N*3) [2]=lr(f32,1) [3]=sigma(f32,N)
//       [4]=target_norm(f32,N*3) [5]=voxel_array(f32,8*128^3*3)
// d_out: value(f32,N*3) ++ new_voxel(f32,8*128^3*3)

#define GRES 128
#define NBINS (8 * 128 * 128)      // key = t(3)|x(7)|y(7)  (17 bits)
#define SCAN_BLOCKS 512            // 256 bins per block
constexpr float RMIN_F = -1.5f;
constexpr float STEP_F = 3.0f / 128.0f;  // exact in fp32

__global__ __launch_bounds__(256) void key_hist_kernel(
    const int* __restrict__ t, const float* __restrict__ pos,
    unsigned* __restrict__ keys, unsigned* __restrict__ hist, int N)
{
    int i = blockIdx.x * blockDim.x + threadIdx.x;
    if (i >= N) return;
    float px = pos[3 * i + 0] - RMIN_F;
    float py = pos[3 * i + 1] - RMIN_F;
    int cx = min((int)floorf(px / STEP_F), GRES - 1);
    int cy = min((int)floorf(py / STEP_F), GRES - 1);
    unsigned key  = ((unsigned)t[i] << 14) | ((unsigned)cx << 7) | (unsigned)cy;
    unsigned rank = atomicAdd(&hist[key], 1u);       // free within-bin rank
    keys[i] = (key << 15) | rank;                    // 17b key | 15b rank
}

// scanA: per-block local exclusive scan of 256 bins + block total.
__global__ __launch_bounds__(256) void scanA_kernel(
    const unsigned* __restrict__ hist, unsigned* __restrict__ binstart,
    unsigned* __restrict__ partial)
{
    __shared__ unsigned sh[256];
    const int tid = threadIdx.x;
    const int gid = blockIdx.x * 256 + tid;
    unsigned x = hist[gid];
    sh[tid] = x;
    __syncthreads();
    for (int off = 1; off < 256; off <<= 1) {
        unsigned v = (tid >= off) ? sh[tid - off] : 0u;
        __syncthreads();
        sh[tid] += v;
        __syncthreads();
    }
    binstart[gid] = sh[tid] - x;               // local exclusive
    if (tid == 255) partial[blockIdx.x] = sh[255];
}

// scanC: each block reduces partial[0..blockIdx) itself (<=512 u32, L2-hot)
// and applies the offset + sentinel.  (Replaces the old scanB+scanC pair.)
__global__ __launch_bounds__(256) void scanC_kernel(
    unsigned* __restrict__ binstart, const unsigned* __restrict__ partial, int N)
{
    __shared__ unsigned s_w[4];
    unsigned loc = 0;
    for (int i = threadIdx.x; i < blockIdx.x; i += 256) loc += partial[i];
    #pragma unroll
    for (int off = 32; off > 0; off >>= 1) loc += __shfl_down(loc, off);
    if ((threadIdx.x & 63) == 0) s_w[threadIdx.x >> 6] = loc;
    __syncthreads();
    const unsigned off0 = s_w[0] + s_w[1] + s_w[2] + s_w[3];
    const int gid = blockIdx.x * 256 + threadIdx.x;
    binstart[gid] += off0;
    if (gid == 0) binstart[NBINS] = (unsigned)N;
}

__global__ __launch_bounds__(256) void scatter_kernel(
    const float* __restrict__ pos, const float* __restrict__ lr_p,
    const float* __restrict__ sigma, const float* __restrict__ target,
    const unsigned* __restrict__ keys, const unsigned* __restrict__ binstart,
    uint4* __restrict__ sorted, int N)
{
    int i = blockIdx.x * blockDim.x + threadIdx.x;
    if (i >= N) return;
    unsigned kr   = keys[i];
    unsigned key  = kr >> 15;
    unsigned rank = kr & 0x7fffu;
    unsigned slot = binstart[key] + rank;            // no atomics

    float px = pos[3 * i + 0] - RMIN_F;
    float py = pos[3 * i + 1] - RMIN_F;
    float pz = pos[3 * i + 2] - RMIN_F;
    float u = fmodf(px, STEP_F) / STEP_F;
    float v = fmodf(py, STEP_F) / STEP_F;
    float w = fmodf(pz, STEP_F) / STEP_F;
    int   mz = min((int)floorf(pz / STEP_F), GRES - 1);

    unsigned qu = (unsigned)(u * 2047.0f + 0.5f);
    unsigned qv = (unsigned)(v * 2047.0f + 0.5f);
    unsigned qw = (unsigned)(w * 1023.0f + 0.5f);

    float lrsw = lr_p[0] * (1.0f - __expf(-sigma[i]));

    unsigned hx = (unsigned)__half_as_ushort(__float2half(target[3 * i + 0]));
    unsigned hy = (unsigned)__half_as_ushort(__float2half(target[3 * i + 1]));
    unsigned hz = (unsigned)__half_as_ushort(__float2half(target[3 * i + 2]));
    unsigned hl = (unsigned)__half_as_ushort(__float2half(lrsw));

    uint4 p;
    p.x = (qu << 21) | (qv << 10) | qw;
    p.y = ((unsigned)i << 7) | (unsigned)mz;        // idx:20 | mz:7
    p.z = hx | (hy << 16);
    p.w = hz | (hl << 16);
    sorted[slot] = p;
}

__global__ __launch_bounds__(256) void brick_kernel(
    const unsigned* __restrict__ binstart,
    const uint4*    __restrict__ sorted,
    const float*    __restrict__ voxel_in,
    float*          __restrict__ out_value,
    float*          __restrict__ out_voxel)
{
    // Per owned voxel: [S_lam, S_lam*tx, S_lam*ty, S_lam*tz]  (32768 B)
    __shared__ __align__(16) float4 s_acc[4 * 4 * 128];
    __shared__ unsigned s_start[25];
    __shared__ unsigned s_pref[26];

    // XCD-slab swizzle: each XCD gets one contiguous t-slab (L2 halo reuse).
    const int vb = ((blockIdx.x & 7) << 10) | (blockIdx.x >> 3);
    const int t  = vb >> 10;
    const int bx = (vb >> 5) & 31;
    const int by = vb & 31;
    const int x0 = bx << 2, y0 = by << 2;
    const int tid = threadIdx.x;
    const size_t tbase = (size_t)t * (GRES * GRES * GRES * 3);

    for (int q = tid; q < 2048; q += 256) s_acc[q] = make_float4(0.f, 0.f, 0.f, 0.f);

    if (tid < 25) {
        int dxb = tid / 5 - 1, dyb = tid % 5 - 1;
        int cx = x0 + dxb, cy = y0 + dyb;
        unsigned st = 0, cnt = 0;
        if (cx >= 0 && cx < GRES && cy >= 0 && cy < GRES) {
            unsigned key = ((unsigned)t << 14) | ((unsigned)cx << 7) | (unsigned)cy;
            st  = binstart[key];
            cnt = binstart[key + 1] - st;
        }
        s_start[tid] = st;
        s_pref[tid + 1] = cnt;
    }
    __syncthreads();
    if (tid == 0) {
        unsigned run = 0;
        s_pref[0] = 0;
        for (int b = 0; b < 25; ++b) {
            run += s_pref[b + 1];
            s_pref[b + 1] = run;
        }
    }
    __syncthreads();
    const int P = (int)s_pref[25];

    for (int j = tid; j < P; j += 256) {
        // binary search: largest b in [0,24] with s_pref[b] <= j
        int b = 0;
        #pragma unroll
        for (int s = 16; s > 0; s >>= 1) {
            int nb = b + s;
            if (nb <= 24 && s_pref[nb] <= (unsigned)j) b = nb;
        }
        const int dxb = b / 5 - 1, dyb = b % 5 - 1;
        const int cx = x0 + dxb, cy = y0 + dyb;
        const unsigned g = s_start[b] + ((unsigned)j - s_pref[b]);

        const uint4 p = sorted[g];
        const float u = (float)(p.x >> 21)           * (1.0f / 2047.0f);
        const float v = (float)((p.x >> 10) & 2047u) * (1.0f / 2047.0f);
        const float w = (float)(p.x & 1023u)         * (1.0f / 1023.0f);
        const int  mz  = (int)(p.y & 127u);
        const int  idx = (int)(p.y >> 7);
        const float tx = __half2float(__ushort_as_half((unsigned short)(p.z & 0xffffu)));
        const float ty = __half2float(__ushort_as_half((unsigned short)(p.z >> 16)));
        const float tz = __half2float(__ushort_as_half((unsigned short)(p.w & 0xffffu)));
        const float lrsw = __half2float(__ushort_as_half((unsigned short)(p.w >> 16)));

        const int xs1 = min(cx + 1, GRES - 1);
        const int ys1 = min(cy + 1, GRES - 1);
        const int zs1 = min(mz + 1, GRES - 1);

        float c[8];
        c[0] = (1.f - u) * (1.f - v) * (1.f - w);
        c[1] =        u  * (1.f - v) * (1.f - w);
        c[2] = (1.f - u) *        v  * (1.f - w);
        c[3] =        u  *        v  * (1.f - w);
        c[4] = (1.f - u) * (1.f - v) *        w;
        c[5] =        u  * (1.f - v) *        w;
        c[6] = (1.f - u) *        v  *        w;
        c[7] =        u  *        v  *        w;

        const bool owner = (dxb >= 0) && (dyb >= 0);

        // Only OWNED events need corner values (for the per-point 'value'
        // output).  Two-phase: issue all 8 gathers first (8-deep MLP), then
        // the FMAs.  Halo events skip global memory entirely.
        if (owner) {
            float a[8][3];
            #pragma unroll
            for (int k = 0; k < 8; ++k) {
                const int xi = (k & 1) ? xs1 : cx;
                const int yi = (k & 2) ? ys1 : cy;
                const int zi = (k & 4) ? zs1 : mz;
                const float* vp = voxel_in + tbase + (((size_t)xi * GRES + yi) * GRES + zi) * 3;
                a[k][0] = vp[0];
                a[k][1] = vp[1];
                a[k][2] = vp[2];
            }
            float vx = 0.f, vy = 0.f, vz = 0.f;
            #pragma unroll
            for (int k = 0; k < 8; ++k) {
                vx += c[k] * a[k][0];
                vy += c[k] * a[k][1];
                vz += c[k] * a[k][2];
            }
            out_value[3 * idx + 0] = vx;
            out_value[3 * idx + 1] = vy;
            out_value[3 * idx + 2] = vz;
        }

        // S-form scatter: per in-brick corner accumulate lam and lam*target.
        #pragma unroll
        for (int k = 0; k < 8; ++k) {
            const int xi = (k & 1) ? xs1 : cx;
            const int yi = (k & 2) ? ys1 : cy;
            const int sxi = xi - x0, syi = yi - y0;
            if (sxi >= 0 && sxi < 4 && syi >= 0 && syi < 4) {
                const int zi = (k & 4) ? zs1 : mz;
                const float lam = 1.0f / (1.0f + __expf(-lrsw * c[k]));
                float* sa = (float*)&s_acc[(sxi * 4 + syi) * 128 + zi];
                atomicAdd(sa + 0, lam);
                atomicAdd(sa + 1, lam * tx);
                atomicAdd(sa + 2, lam * ty);
                atomicAdd(sa + 3, lam * tz);
            }
        }
    }
    __syncthreads();

    // Coalesced write-out: out = a*(1 - S_lam) + S_lamt   (a is L2/L3-hot).
    for (int q = tid; q < 2048; q += 256) {
        const int col = q >> 7;           // sxi*4 + syi
        const int zi  = q & 127;
        const int ox = col >> 2, oy = col & 3;
        const size_t coff = tbase + (size_t)(x0 + ox) * 49152
                                  + (size_t)(y0 + oy) * 384 + 3 * (size_t)zi;
        const float4 s = s_acc[q];
        const float ax = voxel_in[coff + 0];
        const float ay = voxel_in[coff + 1];
        const float az = voxel_in[coff + 2];
        out_voxel[coff + 0] = ax + s.y - s.x * ax;
        out_voxel[coff + 1] = ay + s.z - s.x * ay;
        out_voxel[coff + 2] = az + s.w - s.x * az;
    }
}

extern "C" void kernel_launch(void* const* d_in, const int* in_sizes, int n_in,
                              void* d_out, int out_size, void* d_ws, size_t ws_size,
                              hipStream_t stream) {
    const int*   t      = (const int*)  d_in[0];
    const float* pos    = (const float*)d_in[1];
    const float* lr     = (const float*)d_in[2];
    const float* sigma  = (const float*)d_in[3];
    const float* target = (const float*)d_in[4];
    const float* voxel  = (const float*)d_in[5];

    const int N = in_sizes[0];              // 1048576 points

    float* out_value = (float*)d_out;
    float* out_voxel = out_value + (size_t)3 * N;

    // ws: sorted(16B*N=16MB) | keys(4MB) | hist | binstart(+1) | partial
    uint4*    sorted   = (uint4*)d_ws;
    unsigned* keys     = (unsigned*)(sorted + (size_t)N);
    unsigned* hist     = keys + N;
    unsigned* binstart = hist + NBINS;
    unsigned* partial  = binstart + (NBINS + 1);

    const int block = 256;
    const int grid  = (N + block - 1) / block;

    hipMemsetAsync(hist, 0, NBINS * sizeof(unsigned), stream);
    key_hist_kernel<<<grid, block, 0, stream>>>(t, pos, keys, hist, N);
    scanA_kernel<<<SCAN_BLOCKS, 256, 0, stream>>>(hist, binstart, partial);
    scanC_kernel<<<SCAN_BLOCKS, 256, 0, stream>>>(binstart, partial, N);
    scatter_kernel<<<grid, block, 0, stream>>>(pos, lr, sigma, target, keys,
                                               binstart, sorted, N);
    brick_kernel<<<8192, 256, 0, stream>>>(binstart, sorted, voxel,
                                           out_value, out_voxel);
}